// Round 1
// baseline (193.120 us; speedup 1.0000x reference)
//
#include <hip/hip_runtime.h>
#include <hip/hip_bf16.h>

typedef __bf16 bf16x8 __attribute__((ext_vector_type(8)));
typedef float  f32x4  __attribute__((ext_vector_type(4)));

#define MFMA16 __builtin_amdgcn_mfma_f32_16x16x32_bf16

__device__ __forceinline__ float fast_tanh(float x) {
    // tanh(x) = 1 - 2/(exp2(2*log2e*x)+1); rcp rel-err ~1e-6, fine vs bf16 noise
    float e = __builtin_amdgcn_exp2f(x * 2.8853900817779268f);
    return 1.0f - 2.0f * __builtin_amdgcn_rcpf(e + 1.0f);
}

__device__ __forceinline__ unsigned short f2bf(float f) {
    unsigned u = __builtin_bit_cast(unsigned, f);
    u += 0x7fffu + ((u >> 16) & 1u);   // RNE
    return (unsigned short)(u >> 16);
}

__global__ __launch_bounds__(512, 2) void rel_kernel(
    const float* __restrict__ fwd, const float* __restrict__ bwd,
    const int* __restrict__ gold_heads, const int* __restrict__ gold_rels,
    const float* __restrict__ WFOH, const float* __restrict__ WFOM,
    const float* __restrict__ rcatBias, const float* __restrict__ rhid2Layer,
    const float* __restrict__ rhid2Bias, const float* __restrict__ routLayer,
    const float* __restrict__ routBias, float* __restrict__ out,
    int E, int NT)
{
    // LDS: all 2D tiles XOR-swizzled with ((row&7)<<4) on the byte offset (G4)
    __shared__ __align__(16) char sh_cat[32 * 512];   // 32 x 256 bf16 (cat tile)
    __shared__ __align__(16) char sh_h  [32 * 512];   // 32 x 256 bf16
    __shared__ __align__(16) char sh_h2 [32 * 256];   // 32 x 128 bf16
    __shared__ __align__(16) char sh_sc [32 * 256];   // 32 x 64 f32
    __shared__ float sh_catf[256];                    // fixup scratch (f32 path)
    __shared__ float sh_hf[256];
    __shared__ float sh_h2f[128];
    __shared__ float sh_scf[64];
    __shared__ int sh_nfix;
    __shared__ int sh_fixlist[8];

    const int tid   = threadIdx.x;
    const int w     = tid >> 6;        // wave 0..7
    const int lane  = tid & 63;
    const int row16 = lane & 15;
    const int g     = lane >> 4;       // 0..3
    const int xm    = (row16 & 7) << 4;

    // ---------------- prologue: weights -> registers (bf16 fragments) -------
    // GEMM1: wave w owns h-cols [32w,32w+32); W1 = [WFOH | WFOM] (256x256)
    bf16x8 w1f[2][8];
    #pragma unroll
    for (int nbl = 0; nbl < 2; ++nbl) {
        int n = 32 * w + 16 * nbl + row16;
        const float* Wsrc = (n < 128) ? WFOH : WFOM;   // wave-uniform
        int col = (n < 128) ? n : (n - 128);
        #pragma unroll
        for (int kk = 0; kk < 8; ++kk) {
            bf16x8 f;
            #pragma unroll
            for (int j = 0; j < 8; ++j) {
                int k = 32 * kk + 8 * g + j;
                f[j] = (__bf16)Wsrc[k * 128 + col];
            }
            w1f[nbl][kk] = f;
        }
    }
    // GEMM2: wave w owns h2-cols [16w,16w+16)
    bf16x8 w2f[8];
    {
        int n2 = 16 * w + row16;
        #pragma unroll
        for (int kk = 0; kk < 8; ++kk) {
            bf16x8 f;
            #pragma unroll
            for (int j = 0; j < 8; ++j) {
                int k = 32 * kk + 8 * g + j;
                f[j] = (__bf16)rhid2Layer[k * 128 + n2];
            }
            w2f[kk] = f;
        }
    }
    // GEMM3: wave w -> (mb3 = w>>2, nb3 = w&3)
    const int mb3 = w >> 2, nb3 = w & 3;
    bf16x8 w3f[4];
    {
        int n3 = 16 * nb3 + row16;
        #pragma unroll
        for (int kk = 0; kk < 4; ++kk) {
            bf16x8 f;
            #pragma unroll
            for (int j = 0; j < 8; ++j) {
                int k = 32 * kk + 8 * g + j;
                f[j] = (__bf16)routLayer[k * 64 + n3];
            }
            w3f[kk] = f;
        }
    }
    const float rcb0 = rcatBias[32 * w + row16];
    const float rcb1 = rcatBias[32 * w + 16 + row16];
    const float r2b  = rhid2Bias[16 * w + row16];
    const float rob  = routBias[16 * nb3 + row16];

    // staging map: thread t -> tile-row sr = t>>4, quarter sq = t&15
    const int sr = tid >> 4;
    const int sq = tid & 15;
    const int xr_st = (sr & 7) << 4;

    float4 pf[4];
    auto load_tile = [&](int t) {
        int e = t * 32 + sr;
        if (e < E) {
            const float* src;
            if (sq < 8) {
                int head = gold_heads[e];
                src = fwd + (size_t)head * 128 + sq * 16;
            } else {
                src = bwd + (size_t)(e + 1) * 128 + (sq - 8) * 16;
            }
            const float4* p4 = reinterpret_cast<const float4*>(src);
            #pragma unroll
            for (int c = 0; c < 4; ++c) pf[c] = p4[c];
        } else {
            #pragma unroll
            for (int c = 0; c < 4; ++c) pf[c] = make_float4(0.f, 0.f, 0.f, 0.f);
        }
    };

    int tile0 = blockIdx.x;
    if (tile0 < NT) load_tile(tile0);

    for (int tile = tile0; tile < NT; tile += gridDim.x) {
        const int e0 = tile * 32;

        // ---- stage cat tile (bf16, swizzled) from prefetch regs ----
        #pragma unroll
        for (int c = 0; c < 4; ++c) {
            uint2 pk;
            pk.x = (unsigned)f2bf(pf[c].x) | ((unsigned)f2bf(pf[c].y) << 16);
            pk.y = (unsigned)f2bf(pf[c].z) | ((unsigned)f2bf(pf[c].w) << 16);
            int off = sr * 512 + ((32 * sq + 8 * c) ^ xr_st);
            *(uint2*)(sh_cat + off) = pk;
        }
        __syncthreads();                       // cat visible

        // prefetch next tile while GEMMs run
        if (tile + gridDim.x < NT) load_tile(tile + gridDim.x);

        // ---- GEMM1: h(32x256) = cat(32x256) @ W1(256x256), tanh(+rcatBias) ----
        f32x4 acc1[2][2];
        #pragma unroll
        for (int a = 0; a < 2; ++a)
            #pragma unroll
            for (int b = 0; b < 2; ++b) acc1[a][b] = (f32x4){0.f, 0.f, 0.f, 0.f};
        #pragma unroll
        for (int kk = 0; kk < 8; ++kk) {
            int ko = (64 * kk + 16 * g) ^ xm;
            bf16x8 a0 = *(const bf16x8*)(sh_cat + row16 * 512 + ko);
            bf16x8 a1 = *(const bf16x8*)(sh_cat + (16 + row16) * 512 + ko);
            acc1[0][0] = MFMA16(a0, w1f[0][kk], acc1[0][0], 0, 0, 0);
            acc1[1][0] = MFMA16(a1, w1f[0][kk], acc1[1][0], 0, 0, 0);
            acc1[0][1] = MFMA16(a0, w1f[1][kk], acc1[0][1], 0, 0, 0);
            acc1[1][1] = MFMA16(a1, w1f[1][kk], acc1[1][1], 0, 0, 0);
        }
        #pragma unroll
        for (int mb = 0; mb < 2; ++mb)
            #pragma unroll
            for (int nbl = 0; nbl < 2; ++nbl) {
                float bias = nbl ? rcb1 : rcb0;
                #pragma unroll
                for (int r = 0; r < 4; ++r) {
                    int row = 16 * mb + 4 * g + r;
                    int col = 32 * w + 16 * nbl + row16;
                    float v = fast_tanh(acc1[mb][nbl][r] + bias);
                    int off = row * 512 + ((2 * col) ^ ((row & 7) << 4));
                    *(unsigned short*)(sh_h + off) = f2bf(v);
                }
            }
        __syncthreads();                       // h visible

        // ---- GEMM2: h2(32x128) = h @ rhid2Layer(256x128), tanh(+rhid2Bias) ----
        f32x4 acc2[2];
        acc2[0] = (f32x4){0.f, 0.f, 0.f, 0.f};
        acc2[1] = (f32x4){0.f, 0.f, 0.f, 0.f};
        #pragma unroll
        for (int kk = 0; kk < 8; ++kk) {
            int ko = (64 * kk + 16 * g) ^ xm;
            bf16x8 a0 = *(const bf16x8*)(sh_h + row16 * 512 + ko);
            bf16x8 a1 = *(const bf16x8*)(sh_h + (16 + row16) * 512 + ko);
            acc2[0] = MFMA16(a0, w2f[kk], acc2[0], 0, 0, 0);
            acc2[1] = MFMA16(a1, w2f[kk], acc2[1], 0, 0, 0);
        }
        #pragma unroll
        for (int mb = 0; mb < 2; ++mb)
            #pragma unroll
            for (int r = 0; r < 4; ++r) {
                int row = 16 * mb + 4 * g + r;
                int col = 16 * w + row16;
                float v = fast_tanh(acc2[mb][r] + r2b);
                int off = row * 256 + ((2 * col) ^ ((row & 7) << 4));
                *(unsigned short*)(sh_h2 + off) = f2bf(v);
            }
        __syncthreads();                       // h2 visible

        // ---- GEMM3: scores(32x64) = h2 @ routLayer(128x64) + routBias ----
        f32x4 acc3 = (f32x4){0.f, 0.f, 0.f, 0.f};
        #pragma unroll
        for (int kk = 0; kk < 4; ++kk) {
            int m = 16 * mb3 + row16;
            int off = m * 256 + ((64 * kk + 16 * g) ^ xm);
            bf16x8 a = *(const bf16x8*)(sh_h2 + off);
            acc3 = MFMA16(a, w3f[kk], acc3, 0, 0, 0);
        }
        if (tid == 0) sh_nfix = 0;
        #pragma unroll
        for (int r = 0; r < 4; ++r) {
            int row = 16 * mb3 + 4 * g + r;
            int col = 16 * nb3 + row16;
            float v = acc3[r] + rob;
            int off = row * 256 + ((4 * col) ^ ((row & 7) << 4));
            *(float*)(sh_sc + off) = v;
        }
        __syncthreads();                       // scores visible, nfix reset

        // ---- epilogue: hinge per edge (16 threads/edge) ----
        {
            int r  = tid >> 4;
            int g4 = tid & 15;
            int e  = e0 + r;
            int off = r * 256 + ((16 * g4) ^ ((r & 7) << 4));
            f32x4 sv = *(const f32x4*)(sh_sc + off);
            int gold = (e < E) ? gold_rels[e] : 0;
            float gs = -3.0e38f, ws = -3.0e38f;
            #pragma unroll
            for (int c = 0; c < 4; ++c) {
                int lab = 4 * g4 + c;
                float v = sv[c];
                if (lab == gold) gs = v; else ws = fmaxf(ws, v);
            }
            #pragma unroll
            for (int o = 1; o < 16; o <<= 1) {
                gs = fmaxf(gs, __shfl_xor(gs, o));
                ws = fmaxf(ws, __shfl_xor(ws, o));
            }
            if (g4 == 0 && e < E) {
                out[e] = (gs < ws + 1.0f) ? (ws - gs) : 0.0f;
                // hinge predicate is discontinuous at margin==1: flag for f32 fixup
                if (fabsf((gs - ws) - 1.0f) < 0.125f) {
                    int idx = atomicAdd(&sh_nfix, 1);
                    if (idx < 8) sh_fixlist[idx] = r;
                }
            }
        }
        __syncthreads();

        // ---- exact f32 recompute of boundary edges (rare, ~1e-3 of edges) ----
        int nf = sh_nfix;
        nf = nf > 8 ? 8 : nf;
        for (int i = 0; i < nf; ++i) {
            int e = e0 + sh_fixlist[i];
            if (tid < 256) {
                int head = gold_heads[e];
                sh_catf[tid] = (tid < 128) ? fwd[(size_t)head * 128 + tid]
                                           : bwd[(size_t)(e + 1) * 128 + (tid - 128)];
            }
            __syncthreads();
            if (tid < 256) {
                const float* base = (tid < 128) ? WFOH : WFOM;
                int col = (tid < 128) ? tid : tid - 128;
                float s = 0.f;
                #pragma unroll 8
                for (int k = 0; k < 256; ++k) s += sh_catf[k] * base[k * 128 + col];
                sh_hf[tid] = tanhf(s + rcatBias[tid]);
            }
            __syncthreads();
            if (tid < 128) {
                float s = 0.f;
                #pragma unroll 8
                for (int k = 0; k < 256; ++k) s += sh_hf[k] * rhid2Layer[k * 128 + tid];
                sh_h2f[tid] = tanhf(s + rhid2Bias[tid]);
            }
            __syncthreads();
            if (tid < 64) {
                float s = 0.f;
                #pragma unroll 8
                for (int k = 0; k < 128; ++k) s += sh_h2f[k] * routLayer[k * 64 + tid];
                sh_scf[tid] = s + routBias[tid];
            }
            __syncthreads();
            if (tid < 64) {
                int gold = gold_rels[e];
                float v = sh_scf[tid];
                float gs = (tid == gold) ? v : -3.0e38f;
                float ws = (tid == gold) ? -3.0e38f : v;
                #pragma unroll
                for (int o = 1; o < 64; o <<= 1) {
                    gs = fmaxf(gs, __shfl_xor(gs, o));
                    ws = fmaxf(ws, __shfl_xor(ws, o));
                }
                if (tid == 0) out[e] = (gs < ws + 1.0f) ? (ws - gs) : 0.0f;
            }
            __syncthreads();
        }
    }
}

extern "C" void kernel_launch(void* const* d_in, const int* in_sizes, int n_in,
                              void* d_out, int out_size, void* d_ws, size_t ws_size,
                              hipStream_t stream) {
    const float* fwd        = (const float*)d_in[0];
    const float* bwd        = (const float*)d_in[1];
    const int*   gold_heads = (const int*)d_in[2];
    const int*   gold_rels  = (const int*)d_in[3];
    const float* WFOH       = (const float*)d_in[4];
    const float* WFOM       = (const float*)d_in[5];
    const float* rcatBias   = (const float*)d_in[7];   // d_in[6] rhidBias unused by reference
    const float* rhid2      = (const float*)d_in[8];
    const float* rhid2Bias  = (const float*)d_in[9];
    const float* rout       = (const float*)d_in[10];
    const float* routBias   = (const float*)d_in[11];
    float* out = (float*)d_out;

    int E = in_sizes[2];
    if (E <= 0) return;
    int NT = (E + 31) / 32;
    int grid = NT < 512 ? NT : 512;

    hipLaunchKernelGGL(rel_kernel, dim3(grid), dim3(512), 0, stream,
                       fwd, bwd, gold_heads, gold_rels, WFOH, WFOM, rcatBias,
                       rhid2, rhid2Bias, rout, routBias, out, E, NT);
}